// Round 22
// baseline (401.954 us; speedup 1.0000x reference)
//
#include <hip/hip_runtime.h>
#include <math.h>

#define NPG 75
#define KDIM 5

typedef _Float16 half8 __attribute__((ext_vector_type(8)));
typedef _Float16 half4 __attribute__((ext_vector_type(4)));
typedef float f32x4 __attribute__((ext_vector_type(4)));

__device__ __forceinline__ float eluf(float v){ return v > 0.f ? v : expf(v) - 1.f; }

__device__ __forceinline__ unsigned fenc(float f){
    unsigned u = __float_as_uint(f);
    return (u & 0x80000000u) ? ~u : (u | 0x80000000u);
}
__device__ __forceinline__ float fdec(unsigned u){
    return (u & 0x80000000u) ? __uint_as_float(u & 0x7FFFFFFFu) : __uint_as_float(~u);
}

// 25 accumulating FMAs with accumulators pinned to arch VGPRs ("v" constraint).
__device__ __forceinline__ void fma25(float (&r)[25], const float (&wx)[5], const float (&wyx)[5]){
    #pragma unroll
    for (int b1 = 0; b1 < 5; b1++)
        #pragma unroll
        for (int b0 = 0; b0 < 5; b0++)
            asm("v_fmac_f32 %0, %1, %2" : "+v"(r[b1 * 5 + b0]) : "v"(wx[b0]), "v"(wyx[b1]));
}

// spline basis: pseudo = cart/(2*amax)+0.5, clip[0,1], *4; 4 corner weights + kernel ids
__device__ __forceinline__ void spline2(float c0, float c1, float am, int* kks, float* wsp){
    float denom = 2.f * fmaxf(am, 1e-12f);
    float p0 = c0 / denom + 0.5f;
    float p1 = c1 / denom + 0.5f;
    p0 = fminf(fmaxf(p0, 0.f), 1.f) * 4.f;
    p1 = fminf(fmaxf(p1, 0.f), 1.f) * 4.f;
    float b0 = fminf(floorf(p0), 3.f);
    float b1 = fminf(floorf(p1), 3.f);
    float f0 = p0 - b0, f1 = p1 - b1;
    int i0 = (int)b0, i1 = (int)b1;
    wsp[0] = (1.f - f0) * (1.f - f1); kks[0] = i0     + KDIM *  i1;
    wsp[1] =        f0  * (1.f - f1); kks[1] = i0 + 1 + KDIM *  i1;
    wsp[2] = (1.f - f0) *        f1 ; kks[2] = i0     + KDIM * (i1 + 1);
    wsp[3] =        f0  *        f1 ; kks[3] = i0 + 1 + KDIM * (i1 + 1);
}

// ---------------- amax phase A: per-block max of |pos[src]-pos[dst]|, plain store ----------------
__global__ __launch_bounds__(256) void amax0_k(
        const float* __restrict__ pos, const int* __restrict__ src,
        const int* __restrict__ dst, int E4, float* __restrict__ pbmax){
    int i = blockIdx.x * 256 + threadIdx.x;
    float cand = 0.f;
    if (i < E4){
        int4 s4 = ((const int4*)src)[i];
        int4 d4 = ((const int4*)dst)[i];
        #pragma unroll
        for (int k = 0; k < 4; k++){
            int s = (&s4.x)[k], d = (&d4.x)[k];
            float c0 = pos[s*2]   - pos[d*2];
            float c1 = pos[s*2+1] - pos[d*2+1];
            cand = fmaxf(cand, fmaxf(fabsf(c0), fabsf(c1)));
        }
    }
    __shared__ float sm[256];
    sm[threadIdx.x] = cand; __syncthreads();
    for (int o = 128; o > 0; o >>= 1){
        if (threadIdx.x < o) sm[threadIdx.x] = fmaxf(sm[threadIdx.x], sm[threadIdx.x + o]);
        __syncthreads();
    }
    if (threadIdx.x == 0) pbmax[blockIdx.x] = sm[0];
}

// ---------------- amax phase B: single-block reduce, plain store of float bits ----------------
__global__ __launch_bounds__(1024) void reduce_max_k(const float* __restrict__ pbmax, int n,
                                                     unsigned* __restrict__ outbits){
    __shared__ float sm[1024];
    float cand = 0.f;
    for (int i = threadIdx.x; i < n; i += 1024) cand = fmaxf(cand, pbmax[i]);
    sm[threadIdx.x] = cand; __syncthreads();
    for (int o = 512; o > 0; o >>= 1){
        if (threadIdx.x < o) sm[threadIdx.x] = fmaxf(sm[threadIdx.x], sm[threadIdx.x + o]);
        __syncthreads();
    }
    if (threadIdx.x == 0) *outbits = __float_as_uint(sm[0]);
}

// ---------------- conv1 (Fin=1->32) + pool1 fused, one block per graph (512 thr) ----------------
__global__ __launch_bounds__(512) void conv1pool1_k(
        const float* __restrict__ x, const float* __restrict__ pos,
        const int* __restrict__ src, const int* __restrict__ dst, int EPG,
        const unsigned* __restrict__ amaxp,
        const float* __restrict__ W1, const float* __restrict__ r1, const float* __restrict__ b1,
        float* __restrict__ px1, float* __restrict__ pp1, float* __restrict__ sv1,
        int* __restrict__ cl1){
    __shared__ float acc[NPG * 25];
    __shared__ float deg[NPG];
    __shared__ float xl[NPG], p0l[NPG], p1l[NPG];
    __shared__ int   cli[NPG];
    __shared__ float W1s[800], r1s[32], b1s[32];
    __shared__ unsigned px[36 * 32];
    __shared__ float cnt[36], ps[72];

    const int b = blockIdx.x, t = threadIdx.x;
    const int n0 = b * NPG, e0 = b * EPG;

    for (int i = t; i < NPG * 25; i += 512) acc[i] = 0.f;
    for (int i = t; i < 36 * 32; i += 512) px[i] = 0u;
    if (t < NPG) deg[t] = 0.f;
    if (t < 36) cnt[t] = 0.f;
    if (t < 72) ps[t] = 0.f;
    for (int i = t; i < 800; i += 512) W1s[i] = W1[i];
    if (t < 32){ r1s[t] = r1[t]; b1s[t] = b1[t]; }
    if (t < NPG){
        float p0 = pos[(n0 + t) * 2], p1 = pos[(n0 + t) * 2 + 1];
        xl[t] = x[n0 + t]; p0l[t] = p0; p1l[t] = p1;
        int c0 = min(max((int)floorf(p0 / 5.f), 0), 5);
        int c1 = min(max((int)floorf(p1 / 5.f), 0), 5);
        int c = c1 * 6 + c0;
        cli[t] = c;
        cl1[n0 + t] = b * 36 + c;
    }
    __syncthreads();
    if (t < NPG){
        int c = cli[t];
        atomicAdd(&cnt[c], 1.f);
        atomicAdd(&ps[c*2],     p0l[t]);
        atomicAdd(&ps[c*2 + 1], p1l[t]);
    }

    const float am = __uint_as_float(*amaxp);
    for (int e = t; e < EPG; e += 512){
        int s = src[e0 + e] - n0;
        int d = dst[e0 + e] - n0;
        float c0 = p0l[s] - p0l[d];
        float c1 = p1l[s] - p1l[d];
        int kks[4]; float wsp[4];
        spline2(c0, c1, am, kks, wsp);
        float xv = xl[s];
        #pragma unroll
        for (int c = 0; c < 4; c++) atomicAdd(&acc[d*25 + kks[c]], wsp[c] * xv);
        atomicAdd(&deg[d], 1.f);
    }
    __syncthreads();

    // transform + elu + pool-max
    for (int idx = t; idx < NPG * 32; idx += 512){
        int i = idx >> 5, o = idx & 31;
        float sum = 0.f;
        #pragma unroll
        for (int k = 0; k < 25; k++) sum += acc[i*25 + k] * W1s[k*32 + o];
        float v = sum / fmaxf(deg[i], 1.f) + xl[i] * r1s[o] + b1s[o];
        v = eluf(v);
        atomicMax(&px[cli[i]*32 + o], fenc(v));
    }
    __syncthreads();

    for (int idx = t; idx < 36 * 32; idx += 512){
        int s_ = idx >> 5;
        float c = cnt[s_];
        px1[(size_t)(b*36)*32 + idx] = (c > 0.f) ? fdec(px[idx]) : 0.f;
    }
    if (t < 36){
        float c = cnt[t], m = fmaxf(c, 1.f);
        pp1[(b*36 + t)*2]     = ps[t*2] / m;
        pp1[(b*36 + t)*2 + 1] = ps[t*2 + 1] / m;
        sv1[b*36 + t] = (c > 0.f) ? 1.f : 0.f;
    }
}

// ---------------- fused dedup + CSR build, one block (1024 thr) per graph ----------------
template<int GG, int NN>
__global__ __launch_bounds__(1024) void dedup_csr_k(
        const int* src_in, const int* dst_in,
        const int* __restrict__ clmap, const unsigned char* __restrict__ kf_in,
        unsigned char* kf_out, int* es_out, int* ed_out,
        const float* __restrict__ pp, int EPG,
        int* __restrict__ easrc, float2* __restrict__ ecart,
        int* __restrict__ rowptr2, int* __restrict__ kcnt, float* __restrict__ pbmax){
    __shared__ unsigned pm[GG * GG];
    __shared__ float degs[GG];
    __shared__ int rs[GG + 1];
    __shared__ int cur[GG];
    __shared__ float red[16];
    __shared__ int   clS[NN];
    __shared__ float ppS[2 * GG];

    const int b = blockIdx.x, t = threadIdx.x;
    const int lane = t & 63, wid = t >> 6;
    const int e0 = b * EPG;
    const int cbase = b * GG;

    for (int i = t; i < GG * GG; i += 1024) pm[i] = 0xFFFFFFFFu;
    if (t < GG) degs[t] = 0.f;
    if (t < NN) clS[t] = clmap[b * NN + t] - cbase;     // local cluster id
    if (t < 2 * GG) ppS[t] = pp[cbase * 2 + t];
    __syncthreads();

    const int niter = (EPG + 1023) / 1024;   // <= 2 for EPG <= 2048
    int la[2], lb[2]; bool lm[2];
    const int nbase = b * NN;
    for (int it = 0; it < niter; it++){
        int e = t + it * 1024;
        lm[it] = false;
        if (e < EPG){
            int a  = clS[src_in[e0 + e] - nbase];
            int bb = clS[dst_in[e0 + e] - nbase];
            la[it] = a; lb[it] = bb;
            es_out[e0 + e] = cbase + a; ed_out[e0 + e] = cbase + bb;
            bool m = (kf_in ? (kf_in[e0 + e] != 0) : true) && (a != bb);
            lm[it] = m;
            if (m) atomicMin(&pm[a * GG + bb], (unsigned)e);
        }
    }
    __syncthreads();

    float cand = 0.f;
    bool kept[2]; float lc0[2], lc1[2];
    for (int it = 0; it < niter; it++){
        int e = t + it * 1024;
        kept[it] = false;
        if (e < EPG){
            bool k = false;
            if (lm[it]) k = (pm[la[it] * GG + lb[it]] == (unsigned)e);
            kept[it] = k;
            if (kf_out) kf_out[e0 + e] = k ? 1 : 0;
            if (k){
                atomicAdd(&degs[lb[it]], 1.f);
                float c0 = ppS[la[it]*2]     - ppS[lb[it]*2];
                float c1 = ppS[la[it]*2 + 1] - ppS[lb[it]*2 + 1];
                lc0[it] = c0; lc1[it] = c1;
                cand = fmaxf(cand, fmaxf(fabsf(c0), fabsf(c1)));
            }
        }
    }
    #pragma unroll
    for (int o = 1; o < 64; o <<= 1) cand = fmaxf(cand, __shfl_xor(cand, o, 64));
    if (lane == 0) red[wid] = cand;
    __syncthreads();
    if (t == 0){
        float m = red[0];
        #pragma unroll
        for (int i = 1; i < 16; i++) m = fmaxf(m, red[i]);
        pbmax[b] = m;
    }
    // wave-parallel exclusive scan of degs (GG <= 64, wave 0)
    if (t < 64){
        int v = (t < GG) ? (int)degs[t] : 0;
        int incl = v;
        #pragma unroll
        for (int o = 1; o < 64; o <<= 1){
            int u = __shfl_up(incl, o, 64);
            if (t >= o) incl += u;
        }
        if (t == 0) rs[0] = 0;
        if (t < GG) rs[t + 1] = incl;
    }
    __syncthreads();
    if (t < GG){
        rowptr2[(cbase + t)*2]     = e0 + rs[t];
        rowptr2[(cbase + t)*2 + 1] = e0 + rs[t + 1];
        cur[t] = rs[t];
    }
    if (t == 0) kcnt[b] = rs[GG];
    __syncthreads();
    for (int it = 0; it < niter; it++){
        if (kept[it]){
            int slot = atomicAdd(&cur[lb[it]], 1);
            easrc[e0 + slot] = cbase + la[it];
            ecart[e0 + slot] = make_float2(lc0[it], lc1[it]);
        }
    }
}

// ---------------- per-slot spline weight precompute (after amax final) ----------------
__global__ void espline_k(const float2* __restrict__ ecart, const unsigned* __restrict__ amaxp,
                          const int* __restrict__ kcnt, int EPG, int E,
                          float* __restrict__ edata){
    int i = blockIdx.x * 256 + threadIdx.x;
    if (i >= E) return;
    int b = i / EPG;
    if (i - b * EPG >= kcnt[b]) return;
    float2 c = ecart[i];
    float am = __uint_as_float(*amaxp);
    float denom = 2.f * fmaxf(am, 1e-12f);
    float p0 = fminf(fmaxf(c.x / denom + 0.5f, 0.f), 1.f) * 4.f;
    float p1 = fminf(fmaxf(c.y / denom + 0.5f, 0.f), 1.f) * 4.f;
    float b0 = fminf(floorf(p0), 3.f);
    float b1 = fminf(floorf(p1), 3.f);
    int i0 = (int)b0, i1 = (int)b1;
    float f0 = p0 - b0, f1 = p1 - b1;
    float wx[5], wy[5];
    #pragma unroll
    for (int k = 0; k < 5; k++){
        wx[k] = (k == i0) ? (1.f - f0) : ((k == i0 + 1) ? f0 : 0.f);
        wy[k] = (k == i1) ? (1.f - f1) : ((k == i1 + 1) ? f1 : 0.f);
    }
    float* d = edata + (size_t)i * 12;
    *(float4*)(d)     = make_float4(wx[0], wx[1], wx[2], wx[3]);
    *(float4*)(d + 4) = make_float4(wx[4], wy[0], wy[1], wy[2]);
    *(float4*)(d + 8) = make_float4(wy[3], wy[4], 0.f, 0.f);
}

// ---------------- generic mid pooling (stage2), one block per graph ----------------
template<int CIN, int G>
__global__ __launch_bounds__(256) void pool_mid_k(
        const float* __restrict__ xin, const float* __restrict__ ppin,
        const float* __restrict__ svin, float size,
        float* __restrict__ pxout, float* __restrict__ ppout, float* __restrict__ svout,
        int* __restrict__ clout){
    __shared__ unsigned px[G * G * 64];
    __shared__ float cnt[G * G], ps[2 * G * G];
    __shared__ int cli[CIN];
    const int b = blockIdx.x, t = threadIdx.x;

    for (int i = t; i < G * G * 64; i += 256) px[i] = 0u;
    if (t < G * G){ cnt[t] = 0.f; ps[t*2] = 0.f; ps[t*2 + 1] = 0.f; }
    if (t < CIN){
        float v  = svin[b*CIN + t];
        float p0 = ppin[(b*CIN + t)*2], p1 = ppin[(b*CIN + t)*2 + 1];
        int c0 = min(max((int)floorf(p0 / size), 0), G - 1);
        int c1 = min(max((int)floorf(p1 / size), 0), G - 1);
        int c = c1 * G + c0;
        cli[t] = (v > 0.f) ? c : -1;
        clout[b*CIN + t] = b * G * G + c;
    }
    __syncthreads();
    if (t < CIN && cli[t] >= 0){
        int c = cli[t];
        atomicAdd(&cnt[c], 1.f);
        atomicAdd(&ps[c*2],     ppin[(b*CIN + t)*2]);
        atomicAdd(&ps[c*2 + 1], ppin[(b*CIN + t)*2 + 1]);
    }
    __syncthreads();
    for (int idx = t; idx < CIN * 64; idx += 256){
        int i = idx >> 6, f = idx & 63;
        if (cli[i] >= 0)
            atomicMax(&px[cli[i]*64 + f], fenc(xin[(size_t)(b*CIN + i)*64 + f]));
    }
    __syncthreads();
    for (int idx = t; idx < G * G * 64; idx += 256){
        int s_ = idx >> 6;
        pxout[(size_t)(b*G*G)*64 + idx] = (cnt[s_] > 0.f) ? fdec(px[idx]) : 0.f;
    }
    if (t < G * G){
        float c = cnt[t], m = fmaxf(c, 1.f);
        ppout[(b*G*G + t)*2]     = ps[t*2] / m;
        ppout[(b*G*G + t)*2 + 1] = ps[t*2 + 1] / m;
        svout[b*G*G + t] = (c > 0.f) ? 1.f : 0.f;
    }
}

// ---------------- W' = [W ; root] -> fp16, swizzled into MFMA B-fragment order ----------------
__global__ void wswz_k(const float* __restrict__ W, const float* __restrict__ root,
                       int FIN, _Float16* __restrict__ Wz){
    int gid = blockIdx.x * 256 + threadIdx.x;
    int KT = 26 * FIN;
    if (gid >= KT * 64) return;
    int k = gid >> 6, n = gid & 63;
    float v = (k < 25 * FIN) ? W[(size_t)k * 64 + n] : root[(size_t)(k - 25 * FIN) * 64 + n];
    int kt = k >> 5, kr = k & 31, quad = kr >> 3, j = kr & 7;
    int lane = (quad << 4) | (n & 15);
    int nt = n >> 4;
    Wz[(((size_t)(kt * 4 + nt) * 64 + lane) << 3) + j] = (_Float16)v;
}

// ---------------- conv2/conv3 phase A: register-accumulated gather, pipelined ----------------
// 4 independent single-wave nodes per 256-thread workgroup (no barriers) -> lifts
// the workgroups/CU cap from ~16 waves to 32 waves resident.
template<int FIN>
__global__ __launch_bounds__(256) void conv_gather_k(
        const float* __restrict__ x, const int* __restrict__ easrc,
        const float* __restrict__ edata,
        const int* __restrict__ rowptr2, int n, _Float16* __restrict__ Aout){
    constexpr int KTOT = 26 * FIN;
    const int lane = threadIdx.x & 63;
    const int node = blockIdx.x * 4 + (threadIdx.x >> 6);
    if (node >= n) return;
    const int row0 = rowptr2[node*2], row1 = rowptr2[node*2 + 1];
    constexpr int STEP = (FIN == 32) ? 2 : 1;
    const int sub = (FIN == 32) ? (lane >> 5) : 0;
    const int f = lane & (FIN - 1);

    float r[25];
    #pragma unroll
    for (int b = 0; b < 25; b++) r[b] = 0.f;

    int iCur = row0 + sub;
    int aNext = 0;
    float4 waC, wbC, wcC;
    float xvCur = 0.f;
    if (iCur < row1){
        int aCur = easrc[iCur];
        const float* d = edata + (size_t)iCur * 12;
        waC = *(const float4*)(d); wbC = *(const float4*)(d + 4); wcC = *(const float4*)(d + 8);
        xvCur = x[(size_t)aCur * FIN + f];
        int i1 = (iCur + STEP < row1) ? iCur + STEP : iCur;
        aNext = easrc[i1];
    }
    for (; iCur < row1; iCur += STEP){
        int iN  = iCur + STEP;
        int iNs = (iN < row1) ? iN : iCur;
        int iN2 = (iN + STEP < row1) ? iN + STEP : iNs;
        const float* dn = edata + (size_t)iNs * 12;
        float4 waN = *(const float4*)(dn);
        float4 wbN = *(const float4*)(dn + 4);
        float4 wcN = *(const float4*)(dn + 8);
        float xvN = x[(size_t)aNext * FIN + f];   // aNext loaded last iteration
        int aN2 = easrc[iN2];
        float wx[5]  = {waC.x, waC.y, waC.z, waC.w, wbC.x};
        float wyx[5] = {wbC.y * xvCur, wbC.z * xvCur, wbC.w * xvCur, wcC.x * xvCur, wcC.y * xvCur};
        fma25(r, wx, wyx);
        waC = waN; wbC = wbN; wcC = wcN; xvCur = xvN; aNext = aN2;
    }

    if (FIN == 32){
        #pragma unroll
        for (int b = 0; b < 25; b++) r[b] += __shfl_xor(r[b], 32, 64);
    }

    float inv = 1.f / (float)max(row1 - row0, 1);
    _Float16* dstrow = Aout + (size_t)node * KTOT;
    if (FIN == 64){
        #pragma unroll
        for (int b = 0; b < 25; b++) dstrow[b * 64 + f] = (_Float16)(r[b] * inv);
        dstrow[25 * 64 + f] = (_Float16)x[(size_t)node * 64 + f];
    } else {
        #pragma unroll
        for (int b = 0; b < 25; b++)
            if ((b & 1) == sub) dstrow[b * 32 + f] = (_Float16)(r[b] * inv);
        if (sub == 0) dstrow[25 * 32 + f] = (_Float16)x[(size_t)node * 32 + f];
    }
}

// ---------------- conv2/conv3 phase B: MFMA GEMM (fp16 in, fp32 acc), split-K ----------------
template<int KTOT, int SPLITK>
__global__ __launch_bounds__(256) void conv_mfma_k(
        const _Float16* __restrict__ A, const _Float16* __restrict__ Wz,
        int M, float* __restrict__ Cpart){
    constexpr int NSTEP = KTOT / SPLITK / 32;   // 13 for both convs
    const int w = threadIdx.x >> 6, lane = threadIdx.x & 63;
    const int m0 = blockIdx.x * 64 + w * 16;
    const int kt0 = blockIdx.y * NSTEP;
    const int quad = lane >> 4;

    f32x4 acc[4];
    #pragma unroll
    for (int nt = 0; nt < 4; nt++) acc[nt] = (f32x4){0.f, 0.f, 0.f, 0.f};

    const half8* __restrict__ Arow = (const half8*)(A + (size_t)(m0 + (lane & 15)) * KTOT);
    const half8* __restrict__ Wp   = (const half8*)Wz + (size_t)kt0 * 4 * 64 + lane;

    for (int kt = 0; kt < NSTEP; kt++){
        half8 a = Arow[(kt0 + kt) * 4 + quad];
        #pragma unroll
        for (int nt = 0; nt < 4; nt++){
            half8 b = Wp[(kt * 4 + nt) * 64];
            acc[nt] = __builtin_amdgcn_mfma_f32_16x16x32_f16(a, b, acc[nt], 0, 0, 0);
        }
    }

    // C/D layout: col = lane&15, row = quad*4 + reg
    float* cp = Cpart + ((size_t)blockIdx.y * M + m0) * 64;
    const int r = quad * 4, c = lane & 15;
    #pragma unroll
    for (int nt = 0; nt < 4; nt++)
        #pragma unroll
        for (int i = 0; i < 4; i++)
            cp[(size_t)(r + i) * 64 + nt * 16 + c] = acc[nt][i];
}

// ---------------- conv epilogue: combine split-K partials + bias + ELU ----------------
template<int SPLITK>
__global__ void conv_epi_k(const float* __restrict__ Cpart, const float* __restrict__ bias,
                           int M, float* __restrict__ out){
    int gid = blockIdx.x * 256 + threadIdx.x;
    if (gid >= M * 64) return;
    int c = gid & 63;
    float v = bias[c];
    #pragma unroll
    for (int s = 0; s < SPLITK; s++) v += Cpart[(size_t)s * M * 64 + gid];
    out[gid] = eluf(v);
}

// ---------------- final pool (size=14, G=2) + MLP head + log_softmax ----------------
__global__ __launch_bounds__(256) void final_k(
        const float* __restrict__ xin, const float* __restrict__ ppin,
        const float* __restrict__ svin,
        const float* __restrict__ fw1, const float* __restrict__ fb1,
        const float* __restrict__ fw2, const float* __restrict__ fb2,
        float* __restrict__ out){
    __shared__ unsigned px[4 * 64];
    __shared__ float cnt[4];
    __shared__ int cli[25];
    __shared__ float xr[256];
    __shared__ float h[128];
    __shared__ float lg[10];
    __shared__ float lse;
    const int b = blockIdx.x, t = threadIdx.x;

    if (t < 4*64) px[t] = 0u;
    if (t < 4) cnt[t] = 0.f;
    if (t < 25){
        float v  = svin[b*25 + t];
        float p0 = ppin[(b*25 + t)*2], p1 = ppin[(b*25 + t)*2 + 1];
        int c0 = min(max((int)floorf(p0 / 14.f), 0), 1);
        int c1 = min(max((int)floorf(p1 / 14.f), 0), 1);
        int c = c1 * 2 + c0;
        cli[t] = (v > 0.f) ? c : -1;
    }
    __syncthreads();
    if (t < 25 && cli[t] >= 0) atomicAdd(&cnt[cli[t]], 1.f);
    __syncthreads();
    for (int idx = t; idx < 25 * 64; idx += 256){
        int i = idx >> 6, f = idx & 63;
        if (cli[i] >= 0)
            atomicMax(&px[cli[i]*64 + f], fenc(xin[(size_t)(b*25 + i)*64 + f]));
    }
    __syncthreads();
    xr[t] = (cnt[t >> 6] > 0.f) ? fdec(px[t]) : 0.f;
    __syncthreads();
    if (t < 128){
        float s = fb1[t];
        const float* wrow = fw1 + (size_t)t * 256;
        #pragma unroll 8
        for (int i = 0; i < 256; i++) s += xr[i] * wrow[i];
        h[t] = eluf(s);
    }
    __syncthreads();
    if (t < 10){
        float s2 = fb2[t];
        const float* w2 = fw2 + (size_t)t * 128;
        for (int j = 0; j < 128; j++) s2 += h[j] * w2[j];
        lg[t] = s2;
    }
    __syncthreads();
    if (t == 0){
        float m = lg[0];
        for (int c = 1; c < 10; c++) m = fmaxf(m, lg[c]);
        float se = 0.f;
        for (int c = 0; c < 10; c++) se += expf(lg[c] - m);
        lse = m + logf(se);
    }
    __syncthreads();
    if (t < 10) out[(size_t)b*10 + t] = lg[t] - lse;
}

extern "C" void kernel_launch(void* const* d_in, const int* in_sizes, int n_in,
                              void* d_out, int out_size, void* d_ws, size_t ws_size,
                              hipStream_t stream) {
    const float* x   = (const float*)d_in[0];
    const float* pos = (const float*)d_in[1];
    const int*   src = (const int*)d_in[2];
    const int*   dst = (const int*)d_in[3];
    const float* W1  = (const float*)d_in[4];
    const float* r1  = (const float*)d_in[5];
    const float* b1  = (const float*)d_in[6];
    const float* W2  = (const float*)d_in[7];
    const float* r2  = (const float*)d_in[8];
    const float* b2  = (const float*)d_in[9];
    const float* W3  = (const float*)d_in[10];
    const float* r3  = (const float*)d_in[11];
    const float* b3  = (const float*)d_in[12];
    const float* fw1 = (const float*)d_in[13];
    const float* fb1 = (const float*)d_in[14];
    const float* fw2 = (const float*)d_in[15];
    const float* fb2 = (const float*)d_in[16];
    float* out = (float*)d_out;

    const int N   = in_sizes[0];
    const int E   = in_sizes[2];
    const int B   = N / NPG;
    const int EPG = E / B;
    const int S1  = B * 36;
    const int S2  = B * 25;

    float* w = (float*)d_ws;
    size_t off = 0;
    auto alloc = [&](size_t nelem){ size_t o = off; off += (nelem + 63) & ~(size_t)63; return o; };

    size_t o_scal = alloc(4);                 // amax0, amax1, amax2 bits
    size_t o_pb   = alloc(8192);              // per-block max scratch
    size_t o_px1  = alloc((size_t)S1 * 32);
    size_t o_pp1  = alloc((size_t)S1 * 2);
    size_t o_sv1  = alloc(S1);
    size_t o_cl1  = alloc(N);
    size_t o_kf1  = alloc((E + 3) / 4);
    size_t o_es1  = alloc(E);
    size_t o_ed1  = alloc(E);
    size_t o_easrc= alloc(E);
    size_t o_ecart= alloc((size_t)2 * E);
    size_t o_edat = alloc((size_t)12 * E);
    size_t o_kcnt = alloc(B);
    size_t o_rp2  = alloc((size_t)2 * S1);
    size_t o_rp3  = alloc((size_t)2 * S2);
    size_t o_out2 = alloc((size_t)S1 * 64);
    size_t o_cl2  = alloc(S1);
    size_t o_px2  = alloc((size_t)S2 * 64);
    size_t o_pp2  = alloc((size_t)S2 * 2);
    size_t o_sv2  = alloc(S2);
    size_t o_out3 = alloc((size_t)S2 * 64);
    size_t o_wz   = alloc((size_t)26 * 64 * 64 / 2 + 64);          // fp16 swizzled W'
    size_t cpElems = (size_t)2 * S1 * 64 > (size_t)4 * S2 * 64 ? (size_t)2 * S1 * 64 : (size_t)4 * S2 * 64;
    size_t o_cp   = alloc(cpElems);           // split-K fp32 partials (union of conv2/conv3)
    size_t accAhalfs = (size_t)S1 * 832 > (size_t)S2 * 1664 ? (size_t)S1 * 832 : (size_t)S2 * 1664;
    size_t o_accA = alloc((accAhalfs + 1) / 2);

    hipMemsetAsync(w + o_scal, 0, 4 * sizeof(float), stream);

    unsigned* scal = (unsigned*)(w + o_scal);
    float*    pb   = w + o_pb;
    _Float16* Wz   = (_Float16*)(w + o_wz);
    _Float16* A16  = (_Float16*)(w + o_accA);
    auto nb = [](long long t){ return (unsigned)((t + 255) / 256); };
    auto nb4 = [](long long t){ return (unsigned)((t + 3) / 4); };

    // stage 1: two-phase amax over original edges (no single-address atomics)
    const int E4 = E / 4;
    const int nbA = (int)nb(E4);
    amax0_k<<<nbA, 256, 0, stream>>>(pos, src, dst, E4, pb);
    reduce_max_k<<<1, 1024, 0, stream>>>(pb, nbA, scal + 0);
    conv1pool1_k<<<B, 512, 0, stream>>>(x, pos, src, dst, EPG, scal + 0, W1, r1, b1,
                                        w + o_px1, w + o_pp1, w + o_sv1, (int*)(w + o_cl1));

    // stage-1 -> stage-2 graph: fused dedup + CSR per graph (clmap slice = 75 nodes)
    dedup_csr_k<36, NPG><<<B, 1024, 0, stream>>>(
        src, dst, (int*)(w + o_cl1), nullptr,
        (unsigned char*)(w + o_kf1), (int*)(w + o_es1), (int*)(w + o_ed1),
        w + o_pp1, EPG, (int*)(w + o_easrc), (float2*)(w + o_ecart),
        (int*)(w + o_rp2), (int*)(w + o_kcnt), pb);
    reduce_max_k<<<1, 1024, 0, stream>>>(pb, B, scal + 1);
    espline_k<<<nb(E), 256, 0, stream>>>((float2*)(w + o_ecart), scal + 1,
                                         (int*)(w + o_kcnt), EPG, E, w + o_edat);

    // conv2 (Fin=32 -> 64), MFMA, split-K = 2
    wswz_k<<<nb(26 * 32 * 64), 256, 0, stream>>>(W2, r2, 32, Wz);
    conv_gather_k<32><<<nb4(S1), 256, 0, stream>>>(
        w + o_px1, (int*)(w + o_easrc), w + o_edat,
        (int*)(w + o_rp2), S1, A16);
    {
        dim3 g(S1 / 64, 2);
        conv_mfma_k<832, 2><<<g, 256, 0, stream>>>(A16, Wz, S1, w + o_cp);
    }
    conv_epi_k<2><<<nb((long long)S1 * 64), 256, 0, stream>>>(w + o_cp, b2, S1, w + o_out2);

    // pool 2 (size=7, G=5)
    pool_mid_k<36, 5><<<B, 256, 0, stream>>>(
        w + o_out2, w + o_pp1, w + o_sv1, 7.f,
        w + o_px2, w + o_pp2, w + o_sv2, (int*)(w + o_cl2));

    // stage-2 -> stage-3 graph (in-place remap of es1/ed1; clmap slice = 36 clusters)
    dedup_csr_k<25, 36><<<B, 1024, 0, stream>>>(
        (int*)(w + o_es1), (int*)(w + o_ed1), (int*)(w + o_cl2), (unsigned char*)(w + o_kf1),
        nullptr, (int*)(w + o_es1), (int*)(w + o_ed1),
        w + o_pp2, EPG, (int*)(w + o_easrc), (float2*)(w + o_ecart),
        (int*)(w + o_rp3), (int*)(w + o_kcnt), pb);
    reduce_max_k<<<1, 1024, 0, stream>>>(pb, B, scal + 2);
    espline_k<<<nb(E), 256, 0, stream>>>((float2*)(w + o_ecart), scal + 2,
                                         (int*)(w + o_kcnt), EPG, E, w + o_edat);

    // conv3 (Fin=64 -> 64), MFMA, split-K = 4
    wswz_k<<<nb(26 * 64 * 64), 256, 0, stream>>>(W3, r3, 64, Wz);
    conv_gather_k<64><<<nb4(S2), 256, 0, stream>>>(
        w + o_px2, (int*)(w + o_easrc), w + o_edat,
        (int*)(w + o_rp3), S2, A16);
    {
        dim3 g(S2 / 64, 4);
        conv_mfma_k<1664, 4><<<g, 256, 0, stream>>>(A16, Wz, S2, w + o_cp);
    }
    conv_epi_k<4><<<nb((long long)S2 * 64), 256, 0, stream>>>(w + o_cp, b3, S2, w + o_out3);

    // final pool + MLP + log_softmax, per graph
    final_k<<<B, 256, 0, stream>>>(w + o_out3, w + o_pp2, w + o_sv2,
                                   fw1, fb1, fw2, fb2, out);
}

// Round 23
// 378.115 us; speedup vs baseline: 1.0630x; 1.0630x over previous
//
#include <hip/hip_runtime.h>
#include <math.h>

#define NPG 75
#define KDIM 5

typedef _Float16 half8 __attribute__((ext_vector_type(8)));
typedef _Float16 half4 __attribute__((ext_vector_type(4)));
typedef float f32x4 __attribute__((ext_vector_type(4)));

__device__ __forceinline__ float eluf(float v){ return v > 0.f ? v : expf(v) - 1.f; }

__device__ __forceinline__ unsigned fenc(float f){
    unsigned u = __float_as_uint(f);
    return (u & 0x80000000u) ? ~u : (u | 0x80000000u);
}
__device__ __forceinline__ float fdec(unsigned u){
    return (u & 0x80000000u) ? __uint_as_float(u & 0x7FFFFFFFu) : __uint_as_float(~u);
}

// 25 accumulating FMAs with accumulators pinned to arch VGPRs ("v" constraint).
__device__ __forceinline__ void fma25(float (&r)[25], const float (&wx)[5], const float (&wyx)[5]){
    #pragma unroll
    for (int b1 = 0; b1 < 5; b1++)
        #pragma unroll
        for (int b0 = 0; b0 < 5; b0++)
            asm("v_fmac_f32 %0, %1, %2" : "+v"(r[b1 * 5 + b0]) : "v"(wx[b0]), "v"(wyx[b1]));
}

// spline basis: pseudo = cart/(2*amax)+0.5, clip[0,1], *4; 4 corner weights + kernel ids
__device__ __forceinline__ void spline2(float c0, float c1, float am, int* kks, float* wsp){
    float denom = 2.f * fmaxf(am, 1e-12f);
    float p0 = c0 / denom + 0.5f;
    float p1 = c1 / denom + 0.5f;
    p0 = fminf(fmaxf(p0, 0.f), 1.f) * 4.f;
    p1 = fminf(fmaxf(p1, 0.f), 1.f) * 4.f;
    float b0 = fminf(floorf(p0), 3.f);
    float b1 = fminf(floorf(p1), 3.f);
    float f0 = p0 - b0, f1 = p1 - b1;
    int i0 = (int)b0, i1 = (int)b1;
    wsp[0] = (1.f - f0) * (1.f - f1); kks[0] = i0     + KDIM *  i1;
    wsp[1] =        f0  * (1.f - f1); kks[1] = i0 + 1 + KDIM *  i1;
    wsp[2] = (1.f - f0) *        f1 ; kks[2] = i0     + KDIM * (i1 + 1);
    wsp[3] =        f0  *        f1 ; kks[3] = i0 + 1 + KDIM * (i1 + 1);
}

// ---------------- amax phase A: per-block max of |pos[src]-pos[dst]|, plain store ----------------
__global__ __launch_bounds__(256) void amax0_k(
        const float* __restrict__ pos, const int* __restrict__ src,
        const int* __restrict__ dst, int E4, float* __restrict__ pbmax){
    int i = blockIdx.x * 256 + threadIdx.x;
    float cand = 0.f;
    if (i < E4){
        int4 s4 = ((const int4*)src)[i];
        int4 d4 = ((const int4*)dst)[i];
        #pragma unroll
        for (int k = 0; k < 4; k++){
            int s = (&s4.x)[k], d = (&d4.x)[k];
            float c0 = pos[s*2]   - pos[d*2];
            float c1 = pos[s*2+1] - pos[d*2+1];
            cand = fmaxf(cand, fmaxf(fabsf(c0), fabsf(c1)));
        }
    }
    __shared__ float sm[256];
    sm[threadIdx.x] = cand; __syncthreads();
    for (int o = 128; o > 0; o >>= 1){
        if (threadIdx.x < o) sm[threadIdx.x] = fmaxf(sm[threadIdx.x], sm[threadIdx.x + o]);
        __syncthreads();
    }
    if (threadIdx.x == 0) pbmax[blockIdx.x] = sm[0];
}

// ---------------- amax phase B: single-block reduce, plain store of float bits ----------------
__global__ __launch_bounds__(1024) void reduce_max_k(const float* __restrict__ pbmax, int n,
                                                     unsigned* __restrict__ outbits){
    __shared__ float sm[1024];
    float cand = 0.f;
    for (int i = threadIdx.x; i < n; i += 1024) cand = fmaxf(cand, pbmax[i]);
    sm[threadIdx.x] = cand; __syncthreads();
    for (int o = 512; o > 0; o >>= 1){
        if (threadIdx.x < o) sm[threadIdx.x] = fmaxf(sm[threadIdx.x], sm[threadIdx.x + o]);
        __syncthreads();
    }
    if (threadIdx.x == 0) *outbits = __float_as_uint(sm[0]);
}

// ---------------- conv1 (Fin=1->32) + pool1 fused, one block per graph (512 thr) ----------------
__global__ __launch_bounds__(512) void conv1pool1_k(
        const float* __restrict__ x, const float* __restrict__ pos,
        const int* __restrict__ src, const int* __restrict__ dst, int EPG,
        const unsigned* __restrict__ amaxp,
        const float* __restrict__ W1, const float* __restrict__ r1, const float* __restrict__ b1,
        float* __restrict__ px1, float* __restrict__ pp1, float* __restrict__ sv1,
        int* __restrict__ cl1){
    __shared__ float acc[NPG * 25];
    __shared__ float deg[NPG];
    __shared__ float xl[NPG], p0l[NPG], p1l[NPG];
    __shared__ int   cli[NPG];
    __shared__ float W1s[800], r1s[32], b1s[32];
    __shared__ unsigned px[36 * 32];
    __shared__ float cnt[36], ps[72];

    const int b = blockIdx.x, t = threadIdx.x;
    const int n0 = b * NPG, e0 = b * EPG;

    for (int i = t; i < NPG * 25; i += 512) acc[i] = 0.f;
    for (int i = t; i < 36 * 32; i += 512) px[i] = 0u;
    if (t < NPG) deg[t] = 0.f;
    if (t < 36) cnt[t] = 0.f;
    if (t < 72) ps[t] = 0.f;
    for (int i = t; i < 800; i += 512) W1s[i] = W1[i];
    if (t < 32){ r1s[t] = r1[t]; b1s[t] = b1[t]; }
    if (t < NPG){
        float p0 = pos[(n0 + t) * 2], p1 = pos[(n0 + t) * 2 + 1];
        xl[t] = x[n0 + t]; p0l[t] = p0; p1l[t] = p1;
        int c0 = min(max((int)floorf(p0 / 5.f), 0), 5);
        int c1 = min(max((int)floorf(p1 / 5.f), 0), 5);
        int c = c1 * 6 + c0;
        cli[t] = c;
        cl1[n0 + t] = b * 36 + c;
    }
    __syncthreads();
    if (t < NPG){
        int c = cli[t];
        atomicAdd(&cnt[c], 1.f);
        atomicAdd(&ps[c*2],     p0l[t]);
        atomicAdd(&ps[c*2 + 1], p1l[t]);
    }

    const float am = __uint_as_float(*amaxp);
    for (int e = t; e < EPG; e += 512){
        int s = src[e0 + e] - n0;
        int d = dst[e0 + e] - n0;
        float c0 = p0l[s] - p0l[d];
        float c1 = p1l[s] - p1l[d];
        int kks[4]; float wsp[4];
        spline2(c0, c1, am, kks, wsp);
        float xv = xl[s];
        #pragma unroll
        for (int c = 0; c < 4; c++) atomicAdd(&acc[d*25 + kks[c]], wsp[c] * xv);
        atomicAdd(&deg[d], 1.f);
    }
    __syncthreads();

    // transform + elu + pool-max
    for (int idx = t; idx < NPG * 32; idx += 512){
        int i = idx >> 5, o = idx & 31;
        float sum = 0.f;
        #pragma unroll
        for (int k = 0; k < 25; k++) sum += acc[i*25 + k] * W1s[k*32 + o];
        float v = sum / fmaxf(deg[i], 1.f) + xl[i] * r1s[o] + b1s[o];
        v = eluf(v);
        atomicMax(&px[cli[i]*32 + o], fenc(v));
    }
    __syncthreads();

    for (int idx = t; idx < 36 * 32; idx += 512){
        int s_ = idx >> 5;
        float c = cnt[s_];
        px1[(size_t)(b*36)*32 + idx] = (c > 0.f) ? fdec(px[idx]) : 0.f;
    }
    if (t < 36){
        float c = cnt[t], m = fmaxf(c, 1.f);
        pp1[(b*36 + t)*2]     = ps[t*2] / m;
        pp1[(b*36 + t)*2 + 1] = ps[t*2 + 1] / m;
        sv1[b*36 + t] = (c > 0.f) ? 1.f : 0.f;
    }
}

// ---------------- fused dedup + CSR build, one block (1024 thr) per graph ----------------
template<int GG, int NN>
__global__ __launch_bounds__(1024) void dedup_csr_k(
        const int* src_in, const int* dst_in,
        const int* __restrict__ clmap, const unsigned char* __restrict__ kf_in,
        unsigned char* kf_out, int* es_out, int* ed_out,
        const float* __restrict__ pp, int EPG,
        int* __restrict__ easrc, float2* __restrict__ ecart,
        int* __restrict__ rowptr2, int* __restrict__ kcnt, float* __restrict__ pbmax){
    __shared__ unsigned pm[GG * GG];
    __shared__ float degs[GG];
    __shared__ int rs[GG + 1];
    __shared__ int cur[GG];
    __shared__ float red[16];
    __shared__ int   clS[NN];
    __shared__ float ppS[2 * GG];

    const int b = blockIdx.x, t = threadIdx.x;
    const int lane = t & 63, wid = t >> 6;
    const int e0 = b * EPG;
    const int cbase = b * GG;

    for (int i = t; i < GG * GG; i += 1024) pm[i] = 0xFFFFFFFFu;
    if (t < GG) degs[t] = 0.f;
    if (t < NN) clS[t] = clmap[b * NN + t] - cbase;     // local cluster id
    if (t < 2 * GG) ppS[t] = pp[cbase * 2 + t];
    __syncthreads();

    const int niter = (EPG + 1023) / 1024;
    int la[2], lb[2]; bool lm[2];
    const int nbase = b * NN;
    for (int it = 0; it < niter; it++){
        int e = t + it * 1024;
        lm[it] = false;
        if (e < EPG){
            int a  = clS[src_in[e0 + e] - nbase];
            int bb = clS[dst_in[e0 + e] - nbase];
            la[it] = a; lb[it] = bb;
            es_out[e0 + e] = cbase + a; ed_out[e0 + e] = cbase + bb;
            bool m = (kf_in ? (kf_in[e0 + e] != 0) : true) && (a != bb);
            lm[it] = m;
            if (m) atomicMin(&pm[a * GG + bb], (unsigned)e);
        }
    }
    __syncthreads();

    float cand = 0.f;
    bool kept[2]; float lc0[2], lc1[2];
    for (int it = 0; it < niter; it++){
        int e = t + it * 1024;
        kept[it] = false;
        if (e < EPG){
            bool k = false;
            if (lm[it]) k = (pm[la[it] * GG + lb[it]] == (unsigned)e);
            kept[it] = k;
            if (kf_out) kf_out[e0 + e] = k ? 1 : 0;
            if (k){
                atomicAdd(&degs[lb[it]], 1.f);
                float c0 = ppS[la[it]*2]     - ppS[lb[it]*2];
                float c1 = ppS[la[it]*2 + 1] - ppS[lb[it]*2 + 1];
                lc0[it] = c0; lc1[it] = c1;
                cand = fmaxf(cand, fmaxf(fabsf(c0), fabsf(c1)));
            }
        }
    }
    #pragma unroll
    for (int o = 1; o < 64; o <<= 1) cand = fmaxf(cand, __shfl_xor(cand, o, 64));
    if (lane == 0) red[wid] = cand;
    __syncthreads();
    if (t == 0){
        float m = red[0];
        #pragma unroll
        for (int i = 1; i < 16; i++) m = fmaxf(m, red[i]);
        pbmax[b] = m;
    }
    // wave-parallel exclusive scan of degs (GG <= 64, wave 0)
    if (t < 64){
        int v = (t < GG) ? (int)degs[t] : 0;
        int incl = v;
        #pragma unroll
        for (int o = 1; o < 64; o <<= 1){
            int u = __shfl_up(incl, o, 64);
            if (t >= o) incl += u;
        }
        if (t == 0) rs[0] = 0;
        if (t < GG) rs[t + 1] = incl;
    }
    __syncthreads();
    if (t < GG){
        rowptr2[(cbase + t)*2]     = e0 + rs[t];
        rowptr2[(cbase + t)*2 + 1] = e0 + rs[t + 1];
        cur[t] = rs[t];
    }
    if (t == 0) kcnt[b] = rs[GG];
    __syncthreads();
    for (int it = 0; it < niter; it++){
        if (kept[it]){
            int slot = atomicAdd(&cur[lb[it]], 1);
            easrc[e0 + slot] = cbase + la[it];
            ecart[e0 + slot] = make_float2(lc0[it], lc1[it]);
        }
    }
}

// ---------------- per-slot spline weight precompute (after amax final) ----------------
// Payload: 8 floats/slot: {wx0..wx3, wy0..wy3}; wx4/wy4 reconstructed as 1-sum.
__global__ void espline_k(const float2* __restrict__ ecart, const unsigned* __restrict__ amaxp,
                          const int* __restrict__ kcnt, int EPG, int E,
                          float* __restrict__ edata){
    int i = blockIdx.x * 256 + threadIdx.x;
    if (i >= E) return;
    int b = i / EPG;
    if (i - b * EPG >= kcnt[b]) return;
    float2 c = ecart[i];
    float am = __uint_as_float(*amaxp);
    float denom = 2.f * fmaxf(am, 1e-12f);
    float p0 = fminf(fmaxf(c.x / denom + 0.5f, 0.f), 1.f) * 4.f;
    float p1 = fminf(fmaxf(c.y / denom + 0.5f, 0.f), 1.f) * 4.f;
    float b0 = fminf(floorf(p0), 3.f);
    float b1 = fminf(floorf(p1), 3.f);
    int i0 = (int)b0, i1 = (int)b1;
    float f0 = p0 - b0, f1 = p1 - b1;
    float wx[5], wy[5];
    #pragma unroll
    for (int k = 0; k < 5; k++){
        wx[k] = (k == i0) ? (1.f - f0) : ((k == i0 + 1) ? f0 : 0.f);
        wy[k] = (k == i1) ? (1.f - f1) : ((k == i1 + 1) ? f1 : 0.f);
    }
    float* d = edata + (size_t)i * 8;
    *(float4*)(d)     = make_float4(wx[0], wx[1], wx[2], wx[3]);
    *(float4*)(d + 4) = make_float4(wy[0], wy[1], wy[2], wy[3]);
}

// ---------------- generic mid pooling (stage2), one block per graph ----------------
template<int CIN, int G>
__global__ __launch_bounds__(256) void pool_mid_k(
        const float* __restrict__ xin, const float* __restrict__ ppin,
        const float* __restrict__ svin, float size,
        float* __restrict__ pxout, float* __restrict__ ppout, float* __restrict__ svout,
        int* __restrict__ clout){
    __shared__ unsigned px[G * G * 64];
    __shared__ float cnt[G * G], ps[2 * G * G];
    __shared__ int cli[CIN];
    const int b = blockIdx.x, t = threadIdx.x;

    for (int i = t; i < G * G * 64; i += 256) px[i] = 0u;
    if (t < G * G){ cnt[t] = 0.f; ps[t*2] = 0.f; ps[t*2 + 1] = 0.f; }
    if (t < CIN){
        float v  = svin[b*CIN + t];
        float p0 = ppin[(b*CIN + t)*2], p1 = ppin[(b*CIN + t)*2 + 1];
        int c0 = min(max((int)floorf(p0 / size), 0), G - 1);
        int c1 = min(max((int)floorf(p1 / size), 0), G - 1);
        int c = c1 * G + c0;
        cli[t] = (v > 0.f) ? c : -1;
        clout[b*CIN + t] = b * G * G + c;
    }
    __syncthreads();
    if (t < CIN && cli[t] >= 0){
        int c = cli[t];
        atomicAdd(&cnt[c], 1.f);
        atomicAdd(&ps[c*2],     ppin[(b*CIN + t)*2]);
        atomicAdd(&ps[c*2 + 1], ppin[(b*CIN + t)*2 + 1]);
    }
    __syncthreads();
    for (int idx = t; idx < CIN * 64; idx += 256){
        int i = idx >> 6, f = idx & 63;
        if (cli[i] >= 0)
            atomicMax(&px[cli[i]*64 + f], fenc(xin[(size_t)(b*CIN + i)*64 + f]));
    }
    __syncthreads();
    for (int idx = t; idx < G * G * 64; idx += 256){
        int s_ = idx >> 6;
        pxout[(size_t)(b*G*G)*64 + idx] = (cnt[s_] > 0.f) ? fdec(px[idx]) : 0.f;
    }
    if (t < G * G){
        float c = cnt[t], m = fmaxf(c, 1.f);
        ppout[(b*G*G + t)*2]     = ps[t*2] / m;
        ppout[(b*G*G + t)*2 + 1] = ps[t*2 + 1] / m;
        svout[b*G*G + t] = (c > 0.f) ? 1.f : 0.f;
    }
}

// ---------------- W' = [W ; root] -> fp16, swizzled into MFMA B-fragment order ----------------
__global__ void wswz_k(const float* __restrict__ W, const float* __restrict__ root,
                       int FIN, _Float16* __restrict__ Wz){
    int gid = blockIdx.x * 256 + threadIdx.x;
    int KT = 26 * FIN;
    if (gid >= KT * 64) return;
    int k = gid >> 6, n = gid & 63;
    float v = (k < 25 * FIN) ? W[(size_t)k * 64 + n] : root[(size_t)(k - 25 * FIN) * 64 + n];
    int kt = k >> 5, kr = k & 31, quad = kr >> 3, j = kr & 7;
    int lane = (quad << 4) | (n & 15);
    int nt = n >> 4;
    Wz[(((size_t)(kt * 4 + nt) * 64 + lane) << 3) + j] = (_Float16)v;
}

// ---------------- conv2/conv3 phase A: register-accumulated gather, pipelined ----------------
// One wave per block (round-21 best config); 8-float payload, wx4/wy4 = 1-sum.
template<int FIN>
__global__ __launch_bounds__(64) void conv_gather_k(
        const float* __restrict__ x, const int* __restrict__ easrc,
        const float* __restrict__ edata,
        const int* __restrict__ rowptr2, int n, _Float16* __restrict__ Aout){
    constexpr int KTOT = 26 * FIN;
    const int lane = threadIdx.x;
    const int node = blockIdx.x;
    const int row0 = rowptr2[node*2], row1 = rowptr2[node*2 + 1];
    constexpr int STEP = (FIN == 32) ? 2 : 1;
    const int sub = (FIN == 32) ? (lane >> 5) : 0;
    const int f = lane & (FIN - 1);

    float r[25];
    #pragma unroll
    for (int b = 0; b < 25; b++) r[b] = 0.f;

    int iCur = row0 + sub;
    int aNext = 0;
    float4 waC, wbC;
    float xvCur = 0.f;
    if (iCur < row1){
        int aCur = easrc[iCur];
        const float* d = edata + (size_t)iCur * 8;
        waC = *(const float4*)(d); wbC = *(const float4*)(d + 4);
        xvCur = x[(size_t)aCur * FIN + f];
        int i1 = (iCur + STEP < row1) ? iCur + STEP : iCur;
        aNext = easrc[i1];
    }
    for (; iCur < row1; iCur += STEP){
        int iN  = iCur + STEP;
        int iNs = (iN < row1) ? iN : iCur;
        int iN2 = (iN + STEP < row1) ? iN + STEP : iNs;
        const float* dn = edata + (size_t)iNs * 8;
        float4 waN = *(const float4*)(dn);
        float4 wbN = *(const float4*)(dn + 4);
        float xvN = x[(size_t)aNext * FIN + f];   // aNext loaded last iteration
        int aN2 = easrc[iN2];
        float wx4 = 1.f - (waC.x + waC.y + waC.z + waC.w);
        float wy4 = 1.f - (wbC.x + wbC.y + wbC.z + wbC.w);
        float wx[5]  = {waC.x, waC.y, waC.z, waC.w, wx4};
        float wyx[5] = {wbC.x * xvCur, wbC.y * xvCur, wbC.z * xvCur, wbC.w * xvCur, wy4 * xvCur};
        fma25(r, wx, wyx);
        waC = waN; wbC = wbN; xvCur = xvN; aNext = aN2;
    }

    if (FIN == 32){
        #pragma unroll
        for (int b = 0; b < 25; b++) r[b] += __shfl_xor(r[b], 32, 64);
    }

    float inv = 1.f / (float)max(row1 - row0, 1);
    _Float16* dstrow = Aout + (size_t)node * KTOT;
    if (FIN == 64){
        #pragma unroll
        for (int b = 0; b < 25; b++) dstrow[b * 64 + f] = (_Float16)(r[b] * inv);
        dstrow[25 * 64 + f] = (_Float16)x[(size_t)node * 64 + f];
    } else {
        #pragma unroll
        for (int b = 0; b < 25; b++)
            if ((b & 1) == sub) dstrow[b * 32 + f] = (_Float16)(r[b] * inv);
        if (sub == 0) dstrow[25 * 32 + f] = (_Float16)x[(size_t)node * 32 + f];
    }
}

// ---------------- conv2/conv3 phase B: MFMA GEMM (fp16 in, fp32 acc), split-K ----------------
template<int KTOT, int SPLITK>
__global__ __launch_bounds__(256) void conv_mfma_k(
        const _Float16* __restrict__ A, const _Float16* __restrict__ Wz,
        int M, float* __restrict__ Cpart){
    constexpr int NSTEP = KTOT / SPLITK / 32;   // 13 for both convs
    const int w = threadIdx.x >> 6, lane = threadIdx.x & 63;
    const int m0 = blockIdx.x * 64 + w * 16;
    const int kt0 = blockIdx.y * NSTEP;
    const int quad = lane >> 4;

    f32x4 acc[4];
    #pragma unroll
    for (int nt = 0; nt < 4; nt++) acc[nt] = (f32x4){0.f, 0.f, 0.f, 0.f};

    const half8* __restrict__ Arow = (const half8*)(A + (size_t)(m0 + (lane & 15)) * KTOT);
    const half8* __restrict__ Wp   = (const half8*)Wz + (size_t)kt0 * 4 * 64 + lane;

    for (int kt = 0; kt < NSTEP; kt++){
        half8 a = Arow[(kt0 + kt) * 4 + quad];
        #pragma unroll
        for (int nt = 0; nt < 4; nt++){
            half8 b = Wp[(kt * 4 + nt) * 64];
            acc[nt] = __builtin_amdgcn_mfma_f32_16x16x32_f16(a, b, acc[nt], 0, 0, 0);
        }
    }

    // C/D layout: col = lane&15, row = quad*4 + reg
    float* cp = Cpart + ((size_t)blockIdx.y * M + m0) * 64;
    const int r = quad * 4, c = lane & 15;
    #pragma unroll
    for (int nt = 0; nt < 4; nt++)
        #pragma unroll
        for (int i = 0; i < 4; i++)
            cp[(size_t)(r + i) * 64 + nt * 16 + c] = acc[nt][i];
}

// ---------------- conv epilogue: combine split-K partials + bias + ELU ----------------
template<int SPLITK>
__global__ void conv_epi_k(const float* __restrict__ Cpart, const float* __restrict__ bias,
                           int M, float* __restrict__ out){
    int gid = blockIdx.x * 256 + threadIdx.x;
    if (gid >= M * 64) return;
    int c = gid & 63;
    float v = bias[c];
    #pragma unroll
    for (int s = 0; s < SPLITK; s++) v += Cpart[(size_t)s * M * 64 + gid];
    out[gid] = eluf(v);
}

// ---------------- final pool (size=14, G=2) + MLP head + log_softmax ----------------
__global__ __launch_bounds__(256) void final_k(
        const float* __restrict__ xin, const float* __restrict__ ppin,
        const float* __restrict__ svin,
        const float* __restrict__ fw1, const float* __restrict__ fb1,
        const float* __restrict__ fw2, const float* __restrict__ fb2,
        float* __restrict__ out){
    __shared__ unsigned px[4 * 64];
    __shared__ float cnt[4];
    __shared__ int cli[25];
    __shared__ float xr[256];
    __shared__ float h[128];
    __shared__ float lg[10];
    __shared__ float lse;
    const int b = blockIdx.x, t = threadIdx.x;

    if (t < 4*64) px[t] = 0u;
    if (t < 4) cnt[t] = 0.f;
    if (t < 25){
        float v  = svin[b*25 + t];
        float p0 = ppin[(b*25 + t)*2], p1 = ppin[(b*25 + t)*2 + 1];
        int c0 = min(max((int)floorf(p0 / 14.f), 0), 1);
        int c1 = min(max((int)floorf(p1 / 14.f), 0), 1);
        int c = c1 * 2 + c0;
        cli[t] = (v > 0.f) ? c : -1;
    }
    __syncthreads();
    if (t < 25 && cli[t] >= 0) atomicAdd(&cnt[cli[t]], 1.f);
    __syncthreads();
    for (int idx = t; idx < 25 * 64; idx += 256){
        int i = idx >> 6, f = idx & 63;
        if (cli[i] >= 0)
            atomicMax(&px[cli[i]*64 + f], fenc(xin[(size_t)(b*25 + i)*64 + f]));
    }
    __syncthreads();
    xr[t] = (cnt[t >> 6] > 0.f) ? fdec(px[t]) : 0.f;
    __syncthreads();
    if (t < 128){
        float s = fb1[t];
        const float* wrow = fw1 + (size_t)t * 256;
        #pragma unroll 8
        for (int i = 0; i < 256; i++) s += xr[i] * wrow[i];
        h[t] = eluf(s);
    }
    __syncthreads();
    if (t < 10){
        float s2 = fb2[t];
        const float* w2 = fw2 + (size_t)t * 128;
        for (int j = 0; j < 128; j++) s2 += h[j] * w2[j];
        lg[t] = s2;
    }
    __syncthreads();
    if (t == 0){
        float m = lg[0];
        for (int c = 1; c < 10; c++) m = fmaxf(m, lg[c]);
        float se = 0.f;
        for (int c = 0; c < 10; c++) se += expf(lg[c] - m);
        lse = m + logf(se);
    }
    __syncthreads();
    if (t < 10) out[(size_t)b*10 + t] = lg[t] - lse;
}

extern "C" void kernel_launch(void* const* d_in, const int* in_sizes, int n_in,
                              void* d_out, int out_size, void* d_ws, size_t ws_size,
                              hipStream_t stream) {
    const float* x   = (const float*)d_in[0];
    const float* pos = (const float*)d_in[1];
    const int*   src = (const int*)d_in[2];
    const int*   dst = (const int*)d_in[3];
    const float* W1  = (const float*)d_in[4];
    const float* r1  = (const float*)d_in[5];
    const float* b1  = (const float*)d_in[6];
    const float* W2  = (const float*)d_in[7];
    const float* r2  = (const float*)d_in[8];
    const float* b2  = (const float*)d_in[9];
    const float* W3  = (const float*)d_in[10];
    const float* r3  = (const float*)d_in[11];
    const float* b3  = (const float*)d_in[12];
    const float* fw1 = (const float*)d_in[13];
    const float* fb1 = (const float*)d_in[14];
    const float* fw2 = (const float*)d_in[15];
    const float* fb2 = (const float*)d_in[16];
    float* out = (float*)d_out;

    const int N   = in_sizes[0];
    const int E   = in_sizes[2];
    const int B   = N / NPG;
    const int EPG = E / B;
    const int S1  = B * 36;
    const int S2  = B * 25;

    float* w = (float*)d_ws;
    size_t off = 0;
    auto alloc = [&](size_t nelem){ size_t o = off; off += (nelem + 63) & ~(size_t)63; return o; };

    size_t o_scal = alloc(4);                 // amax0, amax1, amax2 bits
    size_t o_pb   = alloc(8192);              // per-block max scratch
    size_t o_px1  = alloc((size_t)S1 * 32);
    size_t o_pp1  = alloc((size_t)S1 * 2);
    size_t o_sv1  = alloc(S1);
    size_t o_cl1  = alloc(N);
    size_t o_kf1  = alloc((E + 3) / 4);
    size_t o_es1  = alloc(E);
    size_t o_ed1  = alloc(E);
    size_t o_easrc= alloc(E);
    size_t o_ecart= alloc((size_t)2 * E);
    size_t o_edat = alloc((size_t)8 * E);
    size_t o_kcnt = alloc(B);
    size_t o_rp2  = alloc((size_t)2 * S1);
    size_t o_rp3  = alloc((size_t)2 * S2);
    size_t o_out2 = alloc((size_t)S1 * 64);
    size_t o_cl2  = alloc(S1);
    size_t o_px2  = alloc((size_t)S2 * 64);
    size_t o_pp2  = alloc((size_t)S2 * 2);
    size_t o_sv2  = alloc(S2);
    size_t o_out3 = alloc((size_t)S2 * 64);
    size_t o_wz   = alloc((size_t)26 * 64 * 64 / 2 + 64);          // fp16 swizzled W'
    size_t cpElems = (size_t)2 * S1 * 64 > (size_t)4 * S2 * 64 ? (size_t)2 * S1 * 64 : (size_t)4 * S2 * 64;
    size_t o_cp   = alloc(cpElems);           // split-K fp32 partials (union of conv2/conv3)
    size_t accAhalfs = (size_t)S1 * 832 > (size_t)S2 * 1664 ? (size_t)S1 * 832 : (size_t)S2 * 1664;
    size_t o_accA = alloc((accAhalfs + 1) / 2);

    hipMemsetAsync(w + o_scal, 0, 4 * sizeof(float), stream);

    unsigned* scal = (unsigned*)(w + o_scal);
    float*    pb   = w + o_pb;
    _Float16* Wz   = (_Float16*)(w + o_wz);
    _Float16* A16  = (_Float16*)(w + o_accA);
    auto nb = [](long long t){ return (unsigned)((t + 255) / 256); };

    // stage 1: two-phase amax over original edges (no single-address atomics)
    const int E4 = E / 4;
    const int nbA = (int)nb(E4);
    amax0_k<<<nbA, 256, 0, stream>>>(pos, src, dst, E4, pb);
    reduce_max_k<<<1, 1024, 0, stream>>>(pb, nbA, scal + 0);
    conv1pool1_k<<<B, 512, 0, stream>>>(x, pos, src, dst, EPG, scal + 0, W1, r1, b1,
                                        w + o_px1, w + o_pp1, w + o_sv1, (int*)(w + o_cl1));

    // stage-1 -> stage-2 graph: fused dedup + CSR per graph (clmap slice = 75 nodes)
    dedup_csr_k<36, NPG><<<B, 1024, 0, stream>>>(
        src, dst, (int*)(w + o_cl1), nullptr,
        (unsigned char*)(w + o_kf1), (int*)(w + o_es1), (int*)(w + o_ed1),
        w + o_pp1, EPG, (int*)(w + o_easrc), (float2*)(w + o_ecart),
        (int*)(w + o_rp2), (int*)(w + o_kcnt), pb);
    reduce_max_k<<<1, 1024, 0, stream>>>(pb, B, scal + 1);
    espline_k<<<nb(E), 256, 0, stream>>>((float2*)(w + o_ecart), scal + 1,
                                         (int*)(w + o_kcnt), EPG, E, w + o_edat);

    // conv2 (Fin=32 -> 64), MFMA, split-K = 2
    wswz_k<<<nb(26 * 32 * 64), 256, 0, stream>>>(W2, r2, 32, Wz);
    conv_gather_k<32><<<S1, 64, 0, stream>>>(
        w + o_px1, (int*)(w + o_easrc), w + o_edat,
        (int*)(w + o_rp2), S1, A16);
    {
        dim3 g(S1 / 64, 2);
        conv_mfma_k<832, 2><<<g, 256, 0, stream>>>(A16, Wz, S1, w + o_cp);
    }
    conv_epi_k<2><<<nb((long long)S1 * 64), 256, 0, stream>>>(w + o_cp, b2, S1, w + o_out2);

    // pool 2 (size=7, G=5)
    pool_mid_k<36, 5><<<B, 256, 0, stream>>>(
        w + o_out2, w + o_pp1, w + o_sv1, 7.f,
        w + o_px2, w + o_pp2, w + o_sv2, (int*)(w + o_cl2));

    // stage-2 -> stage-3 graph (in-place remap of es1/ed1; clmap slice = 36 clusters)
    dedup_csr_k<25, 36><<<B, 1024, 0, stream>>>(
        (int*)(w + o_es1), (int*)(w + o_ed1), (int*)(w + o_cl2), (unsigned char*)(w + o_kf1),
        nullptr, (int*)(w + o_es1), (int*)(w + o_ed1),
        w + o_pp2, EPG, (int*)(w + o_easrc), (float2*)(w + o_ecart),
        (int*)(w + o_rp3), (int*)(w + o_kcnt), pb);
    reduce_max_k<<<1, 1024, 0, stream>>>(pb, B, scal + 2);
    espline_k<<<nb(E), 256, 0, stream>>>((float2*)(w + o_ecart), scal + 2,
                                         (int*)(w + o_kcnt), EPG, E, w + o_edat);

    // conv3 (Fin=64 -> 64), MFMA, split-K = 4
    wswz_k<<<nb(26 * 64 * 64), 256, 0, stream>>>(W3, r3, 64, Wz);
    conv_gather_k<64><<<S2, 64, 0, stream>>>(
        w + o_px2, (int*)(w + o_easrc), w + o_edat,
        (int*)(w + o_rp3), S2, A16);
    {
        dim3 g(S2 / 64, 4);
        conv_mfma_k<1664, 4><<<g, 256, 0, stream>>>(A16, Wz, S2, w + o_cp);
    }
    conv_epi_k<4><<<nb((long long)S2 * 64), 256, 0, stream>>>(w + o_cp, b3, S2, w + o_out3);

    // final pool + MLP + log_softmax, per graph
    final_k<<<B, 256, 0, stream>>>(w + o_out3, w + o_pp2, w + o_sv2,
                                   fw1, fb1, fw2, fb2, out);
}